// Round 7
// baseline (118.523 us; speedup 1.0000x reference)
//
#include <hip/hip_runtime.h>

typedef unsigned short u16;
typedef __attribute__((ext_vector_type(8))) short bf16x8;
typedef __attribute__((ext_vector_type(4))) float f32x4;

#define S_LEN 2048
#define MTOT  4096   // B*S
#define LOG2E_DIV8 0.1803368784f   // 0.125 * log2(e)

__device__ inline u16 f2bf(float f) {
  union { float f; unsigned u; } x; x.f = f;
  unsigned r = x.u + 0x7fffu + ((x.u >> 16) & 1u);
  return (u16)(r >> 16);
}
__device__ inline float bf2f(u16 u) {
  union { unsigned u; float f; } x; x.u = ((unsigned)u) << 16;
  return x.f;
}

__device__ __forceinline__ unsigned cvtpk_bf16(float lo, float hi) {
  unsigned r;
  asm("v_cvt_pk_bf16_f32 %0, %1, %2" : "=v"(r) : "v"(lo), "v"(hi));
  return r;
}
__device__ __forceinline__ float fexp2(float x) {
  float r;
  asm("v_exp_f32 %0, %1" : "=v"(r) : "v"(x));
  return r;
}
__device__ __forceinline__ float frcp(float x) {
  float r;
  asm("v_rcp_f32 %0, %1" : "=v"(r) : "v"(x));
  return r;
}

// --- gfx950 permlane swaps: D.r2<->S.r0, D.r3<->S.r1 (32) ; D.r1<->S.r0,
//     D.r3<->S.r2 (16), rows = 16-lane groups. Both operands updated.
#define SWAP32(a, b) asm("v_permlane32_swap_b32 %0, %1" : "+v"(a), "+v"(b))
#define SWAP16(a, b) asm("v_permlane16_swap_b32 %0, %1" : "+v"(a), "+v"(b))

// sum of x over the 4 row-groups (lane bits 4-5), result in every lane
__device__ __forceinline__ float sum_lg(float x) {
  float a = x, b = x;
  SWAP32(a, b);
  float s = a + b;
  float c = s, d = s;
  SWAP16(c, d);
  return c + d;
}

typedef __attribute__((address_space(1))) const unsigned int gu32;
typedef __attribute__((address_space(3))) unsigned int lu32;
__device__ __forceinline__ void gload_lds16(const void* g, void* l) {
  __builtin_amdgcn_global_load_lds((gu32*)g, (lu32*)l, 16, 0, 0);
}

#define MFMA16(a, b, c) __builtin_amdgcn_mfma_f32_16x16x32_bf16((a), (b), (c), 0, 0, 0)

// ---------------- cast fp32 -> bf16 (vectorized) ----------------
__global__ __launch_bounds__(256) void cast_bf16(const float* __restrict__ src,
                                                 u16* __restrict__ dst, int n) {
  int i = (blockIdx.x * 256 + threadIdx.x) * 4;
  if (i >= n) return;
  float4 v = *(const float4*)(src + i);
  ushort4 o;
  o.x = f2bf(v.x); o.y = f2bf(v.y); o.z = f2bf(v.z); o.w = f2bf(v.w);
  *(ushort4*)(dst + i) = o;
}

// ---------------- transpose + cast: src[K][N] f32 -> dst[N][K] bf16 ----------
__global__ __launch_bounds__(256) void transcast(const float* __restrict__ src,
                                                 u16* __restrict__ dst, int K, int N) {
  __shared__ float tile[64][65];
  int n0 = blockIdx.x * 64, k0 = blockIdx.y * 64;
  int t = threadIdx.x;
  for (int i = 0; i < 16; ++i) {
    int idx = t + 256 * i;
    int r = idx >> 6, c = idx & 63;
    tile[r][c] = src[(size_t)(k0 + r) * N + n0 + c];
  }
  __syncthreads();
  for (int i = 0; i < 16; ++i) {
    int idx = t + 256 * i;
    int r = idx >> 6, c = idx & 63;
    dst[(size_t)(n0 + r) * K + k0 + c] = f2bf(tile[c][r]);
  }
}

// ---------------- GEMM: C[M][N] = A[M][K] * Bt[N][K]^T + bias ----------------
template<int OUT_BF16>
__global__ __launch_bounds__(256) void gemm_bt(const u16* __restrict__ A,
                                               const u16* __restrict__ Bt,
                                               const float* __restrict__ bias,
                                               void* __restrict__ Cv,
                                               int N, int K,
                                               int qcols, float qscale) {
  __shared__ __align__(16) u16 As[128 * 32];
  __shared__ __align__(16) u16 Bs[128 * 32];
  int t = threadIdx.x;
  int w = t >> 6, l = t & 63;
  int wr = w >> 1, wc = w & 1;
  int lr = l & 15, lg = l >> 4;

  int nwg = gridDim.x * gridDim.y;
  int bid = blockIdx.y * gridDim.x + blockIdx.x;
  int orig = (bid & 7) * (nwg >> 3) + (bid >> 3);   // XCD-chunked remap
  int bx = orig % gridDim.x, by = orig / gridDim.x;
  int m0 = by * 128, n0 = bx * 128;

  f32x4 acc[4][4];
#pragma unroll
  for (int i = 0; i < 4; ++i)
#pragma unroll
    for (int j = 0; j < 4; ++j)
      acc[i][j] = f32x4{0.f, 0.f, 0.f, 0.f};

  int r0 = w * 32 + (l >> 2);
  int r1 = r0 + 16;
  int c0 = (l & 3) ^ ((r0 >> 1) & 3);
  int c1 = (l & 3) ^ ((r1 >> 1) & 3);
  const u16* gA0 = A + (size_t)(m0 + r0) * K + c0 * 8;
  const u16* gA1 = A + (size_t)(m0 + r1) * K + c1 * 8;
  const u16* gB0 = Bt + (size_t)(n0 + r0) * K + c0 * 8;
  const u16* gB1 = Bt + (size_t)(n0 + r1) * K + c1 * 8;
  u16* lA0 = As + (w * 32) * 32;
  u16* lA1 = As + (w * 32 + 16) * 32;
  u16* lB0 = Bs + (w * 32) * 32;
  u16* lB1 = Bs + (w * 32 + 16) * 32;

  for (int k0 = 0; k0 < K; k0 += 32) {
    gload_lds16(gA0 + k0, lA0);
    gload_lds16(gA1 + k0, lA1);
    gload_lds16(gB0 + k0, lB0);
    gload_lds16(gB1 + k0, lB1);
    __syncthreads();
    bf16x8 af[4], bfr[4];
#pragma unroll
    for (int mi = 0; mi < 4; ++mi) {
      int row = wr * 64 + mi * 16 + lr;
      af[mi] = *(const bf16x8*)(As + row * 32 + ((lg ^ ((row >> 1) & 3)) << 3));
    }
#pragma unroll
    for (int ni = 0; ni < 4; ++ni) {
      int row = wc * 64 + ni * 16 + lr;
      bfr[ni] = *(const bf16x8*)(Bs + row * 32 + ((lg ^ ((row >> 1) & 3)) << 3));
    }
    __builtin_amdgcn_s_setprio(1);
#pragma unroll
    for (int mi = 0; mi < 4; ++mi)
#pragma unroll
      for (int ni = 0; ni < 4; ++ni)
        acc[mi][ni] = MFMA16(af[mi], bfr[ni], acc[mi][ni]);
    __builtin_amdgcn_s_setprio(0);
    __syncthreads();
  }

#pragma unroll
  for (int mi = 0; mi < 4; ++mi)
#pragma unroll
    for (int ni = 0; ni < 4; ++ni)
#pragma unroll
      for (int rg = 0; rg < 4; ++rg) {
        int row = m0 + wr * 64 + mi * 16 + lg * 4 + rg;
        int col = n0 + wc * 64 + ni * 16 + lr;
        float v = acc[mi][ni][rg] + bias[col];
        if (col < qcols) v *= qscale;
        if (OUT_BF16) ((u16*)Cv)[(size_t)row * N + col] = f2bf(v);
        else          ((float*)Cv)[(size_t)row * N + col] = v;
      }
}

// ---------------- V pre-transpose: qkv V-slice -> Vt[bh][d][S] bf16 ----------
__global__ __launch_bounds__(256) void vtrans(const u16* __restrict__ qkv,
                                              u16* __restrict__ Vt) {
  __shared__ __align__(16) u16 tile[64][72];
  int s0 = blockIdx.x * 64;
  int bh = blockIdx.y;
  int b = bh >> 4, h = bh & 15;
  int t = threadIdx.x;
  for (int c = 0; c < 2; ++c) {
    int idx = t + 256 * c;
    int r = idx >> 3, off = (idx & 7) * 8;
    *(uint4*)(&tile[r][off]) =
        *(const uint4*)(qkv + (size_t)(b * S_LEN + s0 + r) * 3072 + 2048 + h * 64 + off);
  }
  __syncthreads();
  int d = t >> 2, sb = (t & 3) * 16;
  __align__(16) u16 tmp[16];
  for (int j = 0; j < 16; ++j) tmp[j] = tile[sb + j][d];
  u16* dst = Vt + (size_t)(bh * 64 + d) * S_LEN + s0 + sb;
  *(uint4*)(dst) = *(uint4*)(tmp);
  *(uint4*)(dst + 8) = *(uint4*)(tmp + 8);
}

// ======== attention tile (swapped QK^T -> C[k][q], log2 domain, no-max) =====
// Lane l owns q = (l&15); k-values k = ct*16 + (l>>4)*4 + rg.
// P never touches LDS: cvt_pk packs pairs, then permlane32+16 swaps deliver
// the PV A-fragment layout P[q=lr][k=lg*8+j] directly in registers.
__device__ __forceinline__ void attn_tile(const u16* Ks, const u16* Vs,
                                          bf16x8 q0, bf16x8 q1, f32x4* o,
                                          float& l_run, bool diag,
                                          int w, int l, int lr, int lg) {
  f32x4 s[4];
  __builtin_amdgcn_s_setprio(1);
#pragma unroll
  for (int ct = 0; ct < 4; ++ct) {
    int row = ct * 16 + lr;
    bf16x8 kf0 = *(const bf16x8*)(Ks + ((row * 64 + lg * 8) ^ ((row & 7) << 3)));
    bf16x8 kf1 = *(const bf16x8*)(Ks + ((row * 64 + 32 + lg * 8) ^ ((row & 7) << 3)));
    f32x4 z = f32x4{0.f, 0.f, 0.f, 0.f};
    z = MFMA16(kf0, q0, z);
    z = MFMA16(kf1, q1, z);
    s[ct] = z;
  }
  __builtin_amdgcn_s_setprio(0);
  if (diag) {
    int qrel = w * 16 + lr;
#pragma unroll
    for (int ct = 0; ct < 4; ++ct)
#pragma unroll
      for (int rg = 0; rg < 4; ++rg)
        if ((ct * 16 + lg * 4 + rg) > qrel) s[ct][rg] = -1e30f;
  }
  // p = exp2(s); row sum (VALU-only reduction over lane-groups)
  float ps = 0.f;
#pragma unroll
  for (int ct = 0; ct < 4; ++ct)
#pragma unroll
    for (int rg = 0; rg < 4; ++rg) {
      float p = fexp2(s[ct][rg]);
      s[ct][rg] = p;
      ps += p;
    }
  l_run += sum_lg(ps);

  // pack P to bf16 words W[ct][i] covering k = ct*16 + lg*4 + 2i..2i+1
  unsigned W00 = cvtpk_bf16(s[0][0], s[0][1]);
  unsigned W01 = cvtpk_bf16(s[0][2], s[0][3]);
  unsigned W10 = cvtpk_bf16(s[1][0], s[1][1]);
  unsigned W11 = cvtpk_bf16(s[1][2], s[1][3]);
  unsigned W20 = cvtpk_bf16(s[2][0], s[2][1]);
  unsigned W21 = cvtpk_bf16(s[2][2], s[2][3]);
  unsigned W30 = cvtpk_bf16(s[3][0], s[3][1]);
  unsigned W31 = cvtpk_bf16(s[3][2], s[3][3]);
  // redistribute: after SWAP32;SWAP16 on (a,b): a = [a0,a2,b0,b2], b = [a1,a3,b1,b3]
  SWAP32(W00, W10); SWAP16(W00, W10);   // -> pf0 words d0 (even src), d2 (odd src)
  SWAP32(W01, W11); SWAP16(W01, W11);   // -> pf0 words d1, d3
  SWAP32(W20, W30); SWAP16(W20, W30);   // -> pf1 words d0, d2
  SWAP32(W21, W31); SWAP16(W21, W31);   // -> pf1 words d1, d3
  union { unsigned u[4]; bf16x8 v; } P0, P1;
  P0.u[0] = W00; P0.u[1] = W01; P0.u[2] = W10; P0.u[3] = W11;
  P1.u[0] = W20; P1.u[1] = W21; P1.u[2] = W30; P1.u[3] = W31;

  // PV: o[q][d] += P[q][k] V[k][d]
  __builtin_amdgcn_s_setprio(1);
#pragma unroll
  for (int dt = 0; dt < 4; ++dt) {
    int row = dt * 16 + lr;
    bf16x8 vf0 = *(const bf16x8*)(Vs + ((row * 64 + lg * 8) ^ ((row & 7) << 3)));
    bf16x8 vf1 = *(const bf16x8*)(Vs + ((row * 64 + 32 + lg * 8) ^ ((row & 7) << 3)));
    o[dt] = MFMA16(P0.v, vf0, o[dt]);
    o[dt] = MFMA16(P1.v, vf1, o[dt]);
  }
  __builtin_amdgcn_s_setprio(0);
}

// ---------------- flash attention, causal, paired q-tiles, KV-SPLIT ----------
// grid (32,32)=1024 blocks. Pair (qtA, qtB=31-qtA) split at m into two blocks
// (16/17 tile-units each) -> 4 blocks/CU. No-max softmax => partials combine
// additively; partial o (bf16, unnormalized) + partial l stored per half.
__global__ __launch_bounds__(256, 4) void attn_kernel(const u16* __restrict__ qkv,
                                                      const u16* __restrict__ Vt,
                                                      u16* __restrict__ po0,
                                                      u16* __restrict__ po1,
                                                      float* __restrict__ pl) {
  __shared__ __align__(16) u16 Ks[2][64 * 64];
  __shared__ __align__(16) u16 Vs[2][64 * 64];
  int bid = blockIdx.y * 32 + blockIdx.x;
  int orig = (bid & 7) * 128 + (bid >> 3);   // XCD chunk: 4 bh per XCD
  int half = orig & 1;
  int qtA = (orig >> 1) & 15;
  int bh = orig >> 5;
  int qtB = 31 - qtA;
  int m = (qtA >= 8) ? 8 : (15 - qtA);       // split point: 16/17 units each
  int kts = half ? m : 0;
  int kte = half ? (qtB + 1) : m;
  int b = bh >> 4, h = bh & 15;
  int t = threadIdx.x, w = t >> 6, l = t & 63;
  int lr = l & 15, lg = l >> 4;

  const u16* qbase = qkv + (size_t)b * S_LEN * 3072 + h * 64;
  int qrA = qtA * 64 + w * 16 + lr;
  int qrB = qtB * 64 + w * 16 + lr;
  bf16x8 qA0 = *(const bf16x8*)(qbase + (size_t)qrA * 3072 + lg * 8);
  bf16x8 qA1 = *(const bf16x8*)(qbase + (size_t)qrA * 3072 + 32 + lg * 8);
  bf16x8 qB0 = *(const bf16x8*)(qbase + (size_t)qrB * 3072 + lg * 8);
  bf16x8 qB1 = *(const bf16x8*)(qbase + (size_t)qrB * 3072 + 32 + lg * 8);

  f32x4 oA[4], oB[4];
#pragma unroll
  for (int i = 0; i < 4; ++i) { oA[i] = f32x4{0.f,0.f,0.f,0.f}; oB[i] = f32x4{0.f,0.f,0.f,0.f}; }
  float lA = 0.f, lB = 0.f;

  int r0s = t >> 3, r1s = r0s + 32;
  int soff = (t & 7) * 8;
  int e0 = (r0s * 64 + soff) ^ ((r0s & 7) << 3);
  int e1 = (r1s * 64 + soff) ^ ((r1s & 7) << 3);
  const u16* Kg = qkv + (size_t)b * S_LEN * 3072 + 1024 + h * 64 + soff;
  const u16* Vg = Vt + (size_t)bh * 64 * S_LEN + soff;

  uint4 k0r, k1r, v0r, v1r;
#define ISSUE(KT) {                                                     \
    int kk0 = (KT) * 64;                                                \
    k0r = *(const uint4*)(Kg + (size_t)(kk0 + r0s) * 3072);             \
    k1r = *(const uint4*)(Kg + (size_t)(kk0 + r1s) * 3072);             \
    v0r = *(const uint4*)(Vg + (size_t)r0s * S_LEN + kk0);              \
    v1r = *(const uint4*)(Vg + (size_t)r1s * S_LEN + kk0);              }

  // prologue: tile kts -> LDS buf0; tile kts+1 -> regs
  ISSUE(kts);
  *(uint4*)(Ks[0] + e0) = k0r;
  *(uint4*)(Ks[0] + e1) = k1r;
  *(uint4*)(Vs[0] + e0) = v0r;
  *(uint4*)(Vs[0] + e1) = v1r;
  if (kts + 1 < kte) ISSUE(kts + 1);
  __syncthreads();

  int cur = 0;
  for (int kt = kts; kt < kte; ++kt) {
    if (kt + 1 < kte) {
      u16* Kd = Ks[cur ^ 1];
      u16* Vd = Vs[cur ^ 1];
      *(uint4*)(Kd + e0) = k0r;
      *(uint4*)(Kd + e1) = k1r;
      *(uint4*)(Vd + e0) = v0r;
      *(uint4*)(Vd + e1) = v1r;
    }
    if (kt + 2 < kte) ISSUE(kt + 2);
    const u16* Kc = Ks[cur];
    const u16* Vc = Vs[cur];
    if (kt <= qtA)
      attn_tile(Kc, Vc, qA0, qA1, oA, lA, kt == qtA, w, l, lr, lg);
    attn_tile(Kc, Vc, qB0, qB1, oB, lB, kt == qtB, w, l, lr, lg);
    __syncthreads();
    cur ^= 1;
  }
#undef ISSUE

  // epilogue: store unnormalized partial o (bf16) + partial row-sums l
  u16* po = half ? po1 : po0;
  float* plh = pl + half * 65536;
#pragma unroll
  for (int dt = 0; dt < 4; ++dt)
#pragma unroll
    for (int rg = 0; rg < 4; ++rg) {
      int d = dt * 16 + lr;
      int qA_ = qtA * 64 + w * 16 + lg * 4 + rg;
      int qB_ = qtB * 64 + w * 16 + lg * 4 + rg;
      po[(size_t)(b * S_LEN + qA_) * 1024 + h * 64 + d] = f2bf(oA[dt][rg]);
      po[(size_t)(b * S_LEN + qB_) * 1024 + h * 64 + d] = f2bf(oB[dt][rg]);
    }
  if (lg == 0) {
    plh[bh * 2048 + qtA * 64 + w * 16 + lr] = lA;
    plh[bh * 2048 + qtB * 64 + w * 16 + lr] = lB;
  }
}

// ---------------- combine: out = (po0 + po1) * rcp(l0 + l1) -----------------
// NOTE: out aliases po0 (elementwise read-then-write) -> no __restrict__ there.
__global__ __launch_bounds__(256) void attn_combine(const u16* po0,
                                                    const u16* __restrict__ po1,
                                                    const float* __restrict__ pl,
                                                    u16* out) {
  int i = (blockIdx.x * 256 + threadIdx.x) * 8;
  int row = i >> 10;                 // b*2048 + q
  int h = (i & 1023) >> 6;
  int bh = (row >> 11) * 16 + h;
  int q = row & 2047;
  float r = frcp(pl[bh * 2048 + q] + pl[65536 + bh * 2048 + q]);
  bf16x8 a = *(const bf16x8*)(po0 + i);
  bf16x8 c = *(const bf16x8*)(po1 + i);
  union { u16 u[8]; bf16x8 v; } o;
#pragma unroll
  for (int j = 0; j < 8; ++j)
    o.u[j] = f2bf((bf2f((u16)a[j]) + bf2f((u16)c[j])) * r);
  *(bf16x8*)(out + i) = o.v;
}

// ---------------- launcher ----------------
extern "C" void kernel_launch(void* const* d_in, const int* in_sizes, int n_in,
                              void* d_out, int out_size, void* d_ws, size_t ws_size,
                              hipStream_t stream) {
  const float* x     = (const float*)d_in[0];
  const float* w_qkv = (const float*)d_in[1];
  const float* b_qkv = (const float*)d_in[2];
  const float* w_out = (const float*)d_in[3];
  const float* b_out = (const float*)d_in[4];
  float* out = (float*)d_out;

  // ws layout (56 MB total) with liveness-based aliasing:
  //  0-8   : x_bf (dead after gemm1)  / po1 (attn partial, half 1)
  //  8-14  : wqkvT (dead after gemm1) / pl (attn partial row sums, 0.5 MB)
  //  14-16 : woutT (live until gemm2)
  //  16-40 : qkv
  //  40-48 : Vt
  //  48-56 : po0 (attn partial, half 0) / attnb (combine output, aliases po0)
  char* ws = (char*)d_ws;
  u16* x_bf   = (u16*)(ws);
  u16* po1    = (u16*)(ws);
  u16* wqkvT  = (u16*)(ws + ( 8ull << 20));
  float* pl   = (float*)(ws + ( 8ull << 20));
  u16* woutT  = (u16*)(ws + (14ull << 20));
  u16* qkv    = (u16*)(ws + (16ull << 20));
  u16* Vt     = (u16*)(ws + (40ull << 20));
  u16* po0    = (u16*)(ws + (48ull << 20));
  u16* attnb  = (u16*)(ws + (48ull << 20));

  cast_bf16<<<MTOT * 1024 / 1024, 256, 0, stream>>>(x, x_bf, MTOT * 1024);
  transcast<<<dim3(48, 16), 256, 0, stream>>>(w_qkv, wqkvT, 1024, 3072);
  transcast<<<dim3(16, 16), 256, 0, stream>>>(w_out, woutT, 1024, 1024);
  // Q columns (first 1024) pre-scaled into exp2/log2 domain for attention
  gemm_bt<1><<<dim3(24, 32), 256, 0, stream>>>(x_bf, wqkvT, b_qkv, (void*)qkv,
                                               3072, 1024, 1024, LOG2E_DIV8);
  vtrans<<<dim3(32, 32), 256, 0, stream>>>(qkv, Vt);
  attn_kernel<<<dim3(32, 32), 256, 0, stream>>>(qkv, Vt, po0, po1, pl);
  attn_combine<<<MTOT * 1024 / (256 * 8), 256, 0, stream>>>(po0, po1, pl, attnb);
  gemm_bt<0><<<dim3(8, 32), 256, 0, stream>>>(attnb, woutT, b_out, (void*)out,
                                              1024, 1024, 0, 1.0f);
}

// Round 8
// 113.194 us; speedup vs baseline: 1.0471x; 1.0471x over previous
//
#include <hip/hip_runtime.h>

typedef unsigned short u16;
typedef __attribute__((ext_vector_type(8))) short bf16x8;
typedef __attribute__((ext_vector_type(4))) float f32x4;

#define S_LEN 2048
#define MTOT  4096   // B*S
#define LOG2E_DIV8 0.1803368784f   // 0.125 * log2(e)

__device__ inline u16 f2bf(float f) {
  union { float f; unsigned u; } x; x.f = f;
  unsigned r = x.u + 0x7fffu + ((x.u >> 16) & 1u);
  return (u16)(r >> 16);
}
__device__ inline float bf2f(u16 u) {
  union { unsigned u; float f; } x; x.u = ((unsigned)u) << 16;
  return x.f;
}

__device__ __forceinline__ unsigned cvtpk_bf16(float lo, float hi) {
  unsigned r;
  asm("v_cvt_pk_bf16_f32 %0, %1, %2" : "=v"(r) : "v"(lo), "v"(hi));
  return r;
}
__device__ __forceinline__ float fexp2(float x) {
  float r;
  asm("v_exp_f32 %0, %1" : "=v"(r) : "v"(x));
  return r;
}
__device__ __forceinline__ float frcp(float x) {
  float r;
  asm("v_rcp_f32 %0, %1" : "=v"(r) : "v"(x));
  return r;
}

// --- gfx950 permlane swaps (both operands updated) ---
#define SWAP32(a, b) asm("v_permlane32_swap_b32 %0, %1" : "+v"(a), "+v"(b))
#define SWAP16(a, b) asm("v_permlane16_swap_b32 %0, %1" : "+v"(a), "+v"(b))

// sum of x over the 4 row-groups (lane bits 4-5), result in every lane
__device__ __forceinline__ float sum_lg(float x) {
  float a = x, b = x;
  SWAP32(a, b);
  float s = a + b;
  float c = s, d = s;
  SWAP16(c, d);
  return c + d;
}

typedef __attribute__((address_space(1))) const unsigned int gu32;
typedef __attribute__((address_space(3))) unsigned int lu32;
__device__ __forceinline__ void gload_lds16(const void* g, void* l) {
  __builtin_amdgcn_global_load_lds((gu32*)g, (lu32*)l, 16, 0, 0);
}

#define MFMA16(a, b, c) __builtin_amdgcn_mfma_f32_16x16x32_bf16((a), (b), (c), 0, 0, 0)

// ---------------- cast fp32 -> bf16 (vectorized) ----------------
__global__ __launch_bounds__(256) void cast_bf16(const float* __restrict__ src,
                                                 u16* __restrict__ dst, int n) {
  int i = (blockIdx.x * 256 + threadIdx.x) * 4;
  if (i >= n) return;
  float4 v = *(const float4*)(src + i);
  ushort4 o;
  o.x = f2bf(v.x); o.y = f2bf(v.y); o.z = f2bf(v.z); o.w = f2bf(v.w);
  *(ushort4*)(dst + i) = o;
}

// ------- fused weight transpose+cast: w_qkv[1024][3072] and w_out[1024][1024]
// grid (64,16): bx<48 -> w_qkv tile, else w_out tile. dst[N][K] bf16.
__global__ __launch_bounds__(256) void transcast_w(const float* __restrict__ wqkv,
                                                   const float* __restrict__ wout,
                                                   u16* __restrict__ dqkv,
                                                   u16* __restrict__ dwout) {
  __shared__ float tile[64][65];
  const float* src; u16* dst; int N, n0;
  if (blockIdx.x < 48) { src = wqkv; dst = dqkv; N = 3072; n0 = blockIdx.x * 64; }
  else                 { src = wout; dst = dwout; N = 1024; n0 = (blockIdx.x - 48) * 64; }
  int K = 1024, k0 = blockIdx.y * 64;
  int t = threadIdx.x;
  for (int i = 0; i < 16; ++i) {
    int idx = t + 256 * i;
    int r = idx >> 6, c = idx & 63;
    tile[r][c] = src[(size_t)(k0 + r) * N + n0 + c];
  }
  __syncthreads();
  for (int i = 0; i < 16; ++i) {
    int idx = t + 256 * i;
    int r = idx >> 6, c = idx & 63;
    dst[(size_t)(n0 + r) * K + k0 + c] = f2bf(tile[c][r]);
  }
}

// ---------------- GEMM: C[M][N] = A[M][K] * Bt[N][K]^T + bias ----------------
// 128x128 tile, BK=32, 4 waves (2x2); global_load_lds(16B), swizzled LDS.
template<int OUT_BF16>
__global__ __launch_bounds__(256) void gemm_bt(const u16* __restrict__ A,
                                               const u16* __restrict__ Bt,
                                               const float* __restrict__ bias,
                                               void* __restrict__ Cv,
                                               int N, int K,
                                               int qcols, float qscale) {
  __shared__ __align__(16) u16 As[128 * 32];
  __shared__ __align__(16) u16 Bs[128 * 32];
  int t = threadIdx.x;
  int w = t >> 6, l = t & 63;
  int wr = w >> 1, wc = w & 1;
  int lr = l & 15, lg = l >> 4;

  int nwg = gridDim.x * gridDim.y;
  int bid = blockIdx.y * gridDim.x + blockIdx.x;
  int orig = (bid & 7) * (nwg >> 3) + (bid >> 3);   // XCD-chunked remap
  int bx = orig % gridDim.x, by = orig / gridDim.x;
  int m0 = by * 128, n0 = bx * 128;

  f32x4 acc[4][4];
#pragma unroll
  for (int i = 0; i < 4; ++i)
#pragma unroll
    for (int j = 0; j < 4; ++j)
      acc[i][j] = f32x4{0.f, 0.f, 0.f, 0.f};

  int r0 = w * 32 + (l >> 2);
  int r1 = r0 + 16;
  int c0 = (l & 3) ^ ((r0 >> 1) & 3);
  int c1 = (l & 3) ^ ((r1 >> 1) & 3);
  const u16* gA0 = A + (size_t)(m0 + r0) * K + c0 * 8;
  const u16* gA1 = A + (size_t)(m0 + r1) * K + c1 * 8;
  const u16* gB0 = Bt + (size_t)(n0 + r0) * K + c0 * 8;
  const u16* gB1 = Bt + (size_t)(n0 + r1) * K + c1 * 8;
  u16* lA0 = As + (w * 32) * 32;
  u16* lA1 = As + (w * 32 + 16) * 32;
  u16* lB0 = Bs + (w * 32) * 32;
  u16* lB1 = Bs + (w * 32 + 16) * 32;

  for (int k0 = 0; k0 < K; k0 += 32) {
    gload_lds16(gA0 + k0, lA0);
    gload_lds16(gA1 + k0, lA1);
    gload_lds16(gB0 + k0, lB0);
    gload_lds16(gB1 + k0, lB1);
    __syncthreads();
    bf16x8 af[4], bfr[4];
#pragma unroll
    for (int mi = 0; mi < 4; ++mi) {
      int row = wr * 64 + mi * 16 + lr;
      af[mi] = *(const bf16x8*)(As + row * 32 + ((lg ^ ((row >> 1) & 3)) << 3));
    }
#pragma unroll
    for (int ni = 0; ni < 4; ++ni) {
      int row = wc * 64 + ni * 16 + lr;
      bfr[ni] = *(const bf16x8*)(Bs + row * 32 + ((lg ^ ((row >> 1) & 3)) << 3));
    }
    __builtin_amdgcn_s_setprio(1);
#pragma unroll
    for (int mi = 0; mi < 4; ++mi)
#pragma unroll
      for (int ni = 0; ni < 4; ++ni)
        acc[mi][ni] = MFMA16(af[mi], bfr[ni], acc[mi][ni]);
    __builtin_amdgcn_s_setprio(0);
    __syncthreads();
  }

#pragma unroll
  for (int mi = 0; mi < 4; ++mi)
#pragma unroll
    for (int ni = 0; ni < 4; ++ni)
#pragma unroll
      for (int rg = 0; rg < 4; ++rg) {
        int row = m0 + wr * 64 + mi * 16 + lg * 4 + rg;
        int col = n0 + wc * 64 + ni * 16 + lr;
        float v = acc[mi][ni][rg] + bias[col];
        if (col < qcols) v *= qscale;
        if (OUT_BF16) ((u16*)Cv)[(size_t)row * N + col] = f2bf(v);
        else          ((float*)Cv)[(size_t)row * N + col] = v;
      }
}

// ------------- GEMM small-N variant: 64x128 tile, 4 waves of 64x32 ----------
// For N=1024: grid (8, 64) = 512 blocks (2/CU, 8 waves/CU) vs 256 for 128^2.
__global__ __launch_bounds__(256) void gemm_bt64(const u16* __restrict__ A,
                                                 const u16* __restrict__ Bt,
                                                 const float* __restrict__ bias,
                                                 float* __restrict__ C,
                                                 int N, int K) {
  __shared__ __align__(16) u16 As[64 * 32];
  __shared__ __align__(16) u16 Bs[128 * 32];
  int t = threadIdx.x;
  int w = t >> 6, l = t & 63;
  int lr = l & 15, lg = l >> 4;

  int nwg = gridDim.x * gridDim.y;
  int bid = blockIdx.y * gridDim.x + blockIdx.x;
  int orig = (bid & 7) * (nwg >> 3) + (bid >> 3);   // XCD-chunked remap
  int bx = orig % gridDim.x, by = orig / gridDim.x;
  int m0 = by * 64, n0 = bx * 128;

  f32x4 acc[4][2];
#pragma unroll
  for (int i = 0; i < 4; ++i)
#pragma unroll
    for (int j = 0; j < 2; ++j)
      acc[i][j] = f32x4{0.f, 0.f, 0.f, 0.f};

  // staging: A 64x32 in ONE gload (row = t>>2), B 128x32 in two
  int ra = w * 16 + (l >> 2);               // A row this lane covers
  int ca = (l & 3) ^ ((ra >> 1) & 3);
  int rb1 = ra + 64;
  int cb1 = (l & 3) ^ ((rb1 >> 1) & 3);
  const u16* gA  = A  + (size_t)(m0 + ra) * K + ca * 8;
  const u16* gB0 = Bt + (size_t)(n0 + ra) * K + ca * 8;
  const u16* gB1 = Bt + (size_t)(n0 + rb1) * K + cb1 * 8;
  u16* lA  = As + (w * 16) * 32;
  u16* lB0 = Bs + (w * 16) * 32;
  u16* lB1 = Bs + (64 + w * 16) * 32;

  for (int k0 = 0; k0 < K; k0 += 32) {
    gload_lds16(gA + k0, lA);
    gload_lds16(gB0 + k0, lB0);
    gload_lds16(gB1 + k0, lB1);
    __syncthreads();
    bf16x8 af[4], bfr[2];
#pragma unroll
    for (int mi = 0; mi < 4; ++mi) {
      int row = mi * 16 + lr;
      af[mi] = *(const bf16x8*)(As + row * 32 + ((lg ^ ((row >> 1) & 3)) << 3));
    }
#pragma unroll
    for (int ni = 0; ni < 2; ++ni) {
      int row = w * 32 + ni * 16 + lr;
      bfr[ni] = *(const bf16x8*)(Bs + row * 32 + ((lg ^ ((row >> 1) & 3)) << 3));
    }
    __builtin_amdgcn_s_setprio(1);
#pragma unroll
    for (int mi = 0; mi < 4; ++mi)
#pragma unroll
      for (int ni = 0; ni < 2; ++ni)
        acc[mi][ni] = MFMA16(af[mi], bfr[ni], acc[mi][ni]);
    __builtin_amdgcn_s_setprio(0);
    __syncthreads();
  }

#pragma unroll
  for (int mi = 0; mi < 4; ++mi)
#pragma unroll
    for (int ni = 0; ni < 2; ++ni)
#pragma unroll
      for (int rg = 0; rg < 4; ++rg) {
        int row = m0 + mi * 16 + lg * 4 + rg;
        int col = n0 + w * 32 + ni * 16 + lr;
        C[(size_t)row * N + col] = acc[mi][ni][rg] + bias[col];
      }
}

// ---------------- V pre-transpose: qkv V-slice -> Vt[bh][d][S] bf16 ----------
__global__ __launch_bounds__(256) void vtrans(const u16* __restrict__ qkv,
                                              u16* __restrict__ Vt) {
  __shared__ __align__(16) u16 tile[64][72];
  int s0 = blockIdx.x * 64;
  int bh = blockIdx.y;
  int b = bh >> 4, h = bh & 15;
  int t = threadIdx.x;
  for (int c = 0; c < 2; ++c) {
    int idx = t + 256 * c;
    int r = idx >> 3, off = (idx & 7) * 8;
    *(uint4*)(&tile[r][off]) =
        *(const uint4*)(qkv + (size_t)(b * S_LEN + s0 + r) * 3072 + 2048 + h * 64 + off);
  }
  __syncthreads();
  int d = t >> 2, sb = (t & 3) * 16;
  __align__(16) u16 tmp[16];
  for (int j = 0; j < 16; ++j) tmp[j] = tile[sb + j][d];
  u16* dst = Vt + (size_t)(bh * 64 + d) * S_LEN + s0 + sb;
  *(uint4*)(dst) = *(uint4*)(tmp);
  *(uint4*)(dst + 8) = *(uint4*)(tmp + 8);
}

// ======== attention tile (swapped QK^T -> C[k][q], log2 domain, no-max) =====
__device__ __forceinline__ void attn_tile(const u16* Ks, const u16* Vs,
                                          bf16x8 q0, bf16x8 q1, f32x4* o,
                                          float& l_run, bool diag,
                                          int w, int l, int lr, int lg) {
  f32x4 s[4];
  __builtin_amdgcn_s_setprio(1);
#pragma unroll
  for (int ct = 0; ct < 4; ++ct) {
    int row = ct * 16 + lr;
    bf16x8 kf0 = *(const bf16x8*)(Ks + ((row * 64 + lg * 8) ^ ((row & 7) << 3)));
    bf16x8 kf1 = *(const bf16x8*)(Ks + ((row * 64 + 32 + lg * 8) ^ ((row & 7) << 3)));
    f32x4 z = f32x4{0.f, 0.f, 0.f, 0.f};
    z = MFMA16(kf0, q0, z);
    z = MFMA16(kf1, q1, z);
    s[ct] = z;
  }
  __builtin_amdgcn_s_setprio(0);
  if (diag) {
    int qrel = w * 16 + lr;
#pragma unroll
    for (int ct = 0; ct < 4; ++ct)
#pragma unroll
      for (int rg = 0; rg < 4; ++rg)
        if ((ct * 16 + lg * 4 + rg) > qrel) s[ct][rg] = -1e30f;
  }
  float ps = 0.f;
#pragma unroll
  for (int ct = 0; ct < 4; ++ct)
#pragma unroll
    for (int rg = 0; rg < 4; ++rg) {
      float p = fexp2(s[ct][rg]);
      s[ct][rg] = p;
      ps += p;
    }
  l_run += sum_lg(ps);

  unsigned W00 = cvtpk_bf16(s[0][0], s[0][1]);
  unsigned W01 = cvtpk_bf16(s[0][2], s[0][3]);
  unsigned W10 = cvtpk_bf16(s[1][0], s[1][1]);
  unsigned W11 = cvtpk_bf16(s[1][2], s[1][3]);
  unsigned W20 = cvtpk_bf16(s[2][0], s[2][1]);
  unsigned W21 = cvtpk_bf16(s[2][2], s[2][3]);
  unsigned W30 = cvtpk_bf16(s[3][0], s[3][1]);
  unsigned W31 = cvtpk_bf16(s[3][2], s[3][3]);
  SWAP32(W00, W10); SWAP16(W00, W10);
  SWAP32(W01, W11); SWAP16(W01, W11);
  SWAP32(W20, W30); SWAP16(W20, W30);
  SWAP32(W21, W31); SWAP16(W21, W31);
  union { unsigned u[4]; bf16x8 v; } P0, P1;
  P0.u[0] = W00; P0.u[1] = W01; P0.u[2] = W10; P0.u[3] = W11;
  P1.u[0] = W20; P1.u[1] = W21; P1.u[2] = W30; P1.u[3] = W31;

  __builtin_amdgcn_s_setprio(1);
#pragma unroll
  for (int dt = 0; dt < 4; ++dt) {
    int row = dt * 16 + lr;
    bf16x8 vf0 = *(const bf16x8*)(Vs + ((row * 64 + lg * 8) ^ ((row & 7) << 3)));
    bf16x8 vf1 = *(const bf16x8*)(Vs + ((row * 64 + 32 + lg * 8) ^ ((row & 7) << 3)));
    o[dt] = MFMA16(P0.v, vf0, o[dt]);
    o[dt] = MFMA16(P1.v, vf1, o[dt]);
  }
  __builtin_amdgcn_s_setprio(0);
}

// ---------------- flash attention, causal, paired q-tiles, KV-SPLIT ----------
__global__ __launch_bounds__(256, 4) void attn_kernel(const u16* __restrict__ qkv,
                                                      const u16* __restrict__ Vt,
                                                      u16* __restrict__ po0,
                                                      u16* __restrict__ po1,
                                                      float* __restrict__ pl) {
  __shared__ __align__(16) u16 Ks[2][64 * 64];
  __shared__ __align__(16) u16 Vs[2][64 * 64];
  int bid = blockIdx.y * 32 + blockIdx.x;
  int orig = (bid & 7) * 128 + (bid >> 3);   // XCD chunk: 4 bh per XCD
  int half = orig & 1;
  int qtA = (orig >> 1) & 15;
  int bh = orig >> 5;
  int qtB = 31 - qtA;
  int m = (qtA >= 8) ? 8 : (15 - qtA);       // split point: 16/17 units each
  int kts = half ? m : 0;
  int kte = half ? (qtB + 1) : m;
  int b = bh >> 4, h = bh & 15;
  int t = threadIdx.x, w = t >> 6, l = t & 63;
  int lr = l & 15, lg = l >> 4;

  const u16* qbase = qkv + (size_t)b * S_LEN * 3072 + h * 64;
  int qrA = qtA * 64 + w * 16 + lr;
  int qrB = qtB * 64 + w * 16 + lr;
  bf16x8 qA0 = *(const bf16x8*)(qbase + (size_t)qrA * 3072 + lg * 8);
  bf16x8 qA1 = *(const bf16x8*)(qbase + (size_t)qrA * 3072 + 32 + lg * 8);
  bf16x8 qB0 = *(const bf16x8*)(qbase + (size_t)qrB * 3072 + lg * 8);
  bf16x8 qB1 = *(const bf16x8*)(qbase + (size_t)qrB * 3072 + 32 + lg * 8);

  f32x4 oA[4], oB[4];
#pragma unroll
  for (int i = 0; i < 4; ++i) { oA[i] = f32x4{0.f,0.f,0.f,0.f}; oB[i] = f32x4{0.f,0.f,0.f,0.f}; }
  float lA = 0.f, lB = 0.f;

  int r0s = t >> 3, r1s = r0s + 32;
  int soff = (t & 7) * 8;
  int e0 = (r0s * 64 + soff) ^ ((r0s & 7) << 3);
  int e1 = (r1s * 64 + soff) ^ ((r1s & 7) << 3);
  const u16* Kg = qkv + (size_t)b * S_LEN * 3072 + 1024 + h * 64 + soff;
  const u16* Vg = Vt + (size_t)bh * 64 * S_LEN + soff;

  uint4 k0r, k1r, v0r, v1r;
#define ISSUE(KT) {                                                     \
    int kk0 = (KT) * 64;                                                \
    k0r = *(const uint4*)(Kg + (size_t)(kk0 + r0s) * 3072);             \
    k1r = *(const uint4*)(Kg + (size_t)(kk0 + r1s) * 3072);             \
    v0r = *(const uint4*)(Vg + (size_t)r0s * S_LEN + kk0);              \
    v1r = *(const uint4*)(Vg + (size_t)r1s * S_LEN + kk0);              }

  ISSUE(kts);
  *(uint4*)(Ks[0] + e0) = k0r;
  *(uint4*)(Ks[0] + e1) = k1r;
  *(uint4*)(Vs[0] + e0) = v0r;
  *(uint4*)(Vs[0] + e1) = v1r;
  if (kts + 1 < kte) ISSUE(kts + 1);
  __syncthreads();

  int cur = 0;
  for (int kt = kts; kt < kte; ++kt) {
    if (kt + 1 < kte) {
      u16* Kd = Ks[cur ^ 1];
      u16* Vd = Vs[cur ^ 1];
      *(uint4*)(Kd + e0) = k0r;
      *(uint4*)(Kd + e1) = k1r;
      *(uint4*)(Vd + e0) = v0r;
      *(uint4*)(Vd + e1) = v1r;
    }
    if (kt + 2 < kte) ISSUE(kt + 2);
    const u16* Kc = Ks[cur];
    const u16* Vc = Vs[cur];
    if (kt <= qtA)
      attn_tile(Kc, Vc, qA0, qA1, oA, lA, kt == qtA, w, l, lr, lg);
    attn_tile(Kc, Vc, qB0, qB1, oB, lB, kt == qtB, w, l, lr, lg);
    __syncthreads();
    cur ^= 1;
  }
#undef ISSUE

  u16* po = half ? po1 : po0;
  float* plh = pl + half * 65536;
#pragma unroll
  for (int dt = 0; dt < 4; ++dt)
#pragma unroll
    for (int rg = 0; rg < 4; ++rg) {
      int d = dt * 16 + lr;
      int qA_ = qtA * 64 + w * 16 + lg * 4 + rg;
      int qB_ = qtB * 64 + w * 16 + lg * 4 + rg;
      po[(size_t)(b * S_LEN + qA_) * 1024 + h * 64 + d] = f2bf(oA[dt][rg]);
      po[(size_t)(b * S_LEN + qB_) * 1024 + h * 64 + d] = f2bf(oB[dt][rg]);
    }
  if (lg == 0) {
    plh[bh * 2048 + qtA * 64 + w * 16 + lr] = lA;
    plh[bh * 2048 + qtB * 64 + w * 16 + lr] = lB;
  }
}

// ---------------- combine: out = (po0 + po1) * rcp(l0 + l1) -----------------
__global__ __launch_bounds__(256) void attn_combine(const u16* po0,
                                                    const u16* __restrict__ po1,
                                                    const float* __restrict__ pl,
                                                    u16* out) {
  int i = (blockIdx.x * 256 + threadIdx.x) * 8;
  int row = i >> 10;                 // b*2048 + q
  int h = (i & 1023) >> 6;
  int bh = (row >> 11) * 16 + h;
  int q = row & 2047;
  float r = frcp(pl[bh * 2048 + q] + pl[65536 + bh * 2048 + q]);
  bf16x8 a = *(const bf16x8*)(po0 + i);
  bf16x8 c = *(const bf16x8*)(po1 + i);
  union { u16 u[8]; bf16x8 v; } o;
#pragma unroll
  for (int j = 0; j < 8; ++j)
    o.u[j] = f2bf((bf2f((u16)a[j]) + bf2f((u16)c[j])) * r);
  *(bf16x8*)(out + i) = o.v;
}

// ---------------- launcher ----------------
extern "C" void kernel_launch(void* const* d_in, const int* in_sizes, int n_in,
                              void* d_out, int out_size, void* d_ws, size_t ws_size,
                              hipStream_t stream) {
  const float* x     = (const float*)d_in[0];
  const float* w_qkv = (const float*)d_in[1];
  const float* b_qkv = (const float*)d_in[2];
  const float* w_out = (const float*)d_in[3];
  const float* b_out = (const float*)d_in[4];
  float* out = (float*)d_out;

  // ws layout (56 MB) with liveness-based aliasing:
  //  0-8   : x_bf (dead after gemm1)  / po1
  //  8-14  : wqkvT (dead after gemm1) / pl
  //  14-16 : woutT (live until gemm2)
  //  16-40 : qkv
  //  40-48 : Vt
  //  48-56 : po0 / attnb (combine output aliases po0)
  char* ws = (char*)d_ws;
  u16* x_bf   = (u16*)(ws);
  u16* po1    = (u16*)(ws);
  u16* wqkvT  = (u16*)(ws + ( 8ull << 20));
  float* pl   = (float*)(ws + ( 8ull << 20));
  u16* woutT  = (u16*)(ws + (14ull << 20));
  u16* qkv    = (u16*)(ws + (16ull << 20));
  u16* Vt     = (u16*)(ws + (40ull << 20));
  u16* po0    = (u16*)(ws + (48ull << 20));
  u16* attnb  = (u16*)(ws + (48ull << 20));

  cast_bf16<<<MTOT * 1024 / 1024, 256, 0, stream>>>(x, x_bf, MTOT * 1024);
  transcast_w<<<dim3(64, 16), 256, 0, stream>>>(w_qkv, w_out, wqkvT, woutT);
  // Q columns (first 1024) pre-scaled into exp2/log2 domain for attention
  gemm_bt<1><<<dim3(24, 32), 256, 0, stream>>>(x_bf, wqkvT, b_qkv, (void*)qkv,
                                               3072, 1024, 1024, LOG2E_DIV8);
  vtrans<<<dim3(32, 32), 256, 0, stream>>>(qkv, Vt);
  attn_kernel<<<dim3(32, 32), 256, 0, stream>>>(qkv, Vt, po0, po1, pl);
  attn_combine<<<MTOT * 1024 / (256 * 8), 256, 0, stream>>>(po0, po1, pl, attnb);
  gemm_bt64<<<dim3(8, 64), 256, 0, stream>>>(attnb, woutT, b_out, out, 1024, 1024);
}